// Round 2
// baseline (223.750 us; speedup 1.0000x reference)
//
#include <hip/hip_runtime.h>
#include <hip/hip_bf16.h>

#define DIMV 64

static constexpr float F_EPS  = 1e-7f;
static constexpr float F_MINN = 1e-15f;
static constexpr float F_MAXN = 1.0f - 4e-3f;   // proj maxnorm

__device__ __forceinline__ float wave_sum64(float v) {
#pragma unroll
    for (int off = 32; off > 0; off >>= 1)
        v += __shfl_xor(v, off, 64);
    return v;
}

// block = 1024 per-b blocks, 256 threads = 4 waves.
// wave 0,1 -> h=0 (m 0..15 / 16..31); wave 2,3 -> h=1.
// lane = embedding dim (DIMV==64).
__global__ __launch_bounds__(256) void hpnet_kernel(
        const int*   __restrict__ items,
        const int*   __restrict__ mem_h,
        const int*   __restrict__ mem_r,
        const int*   __restrict__ mem_t,
        const float* __restrict__ ent,
        const float* __restrict__ rel,
        float*       __restrict__ out,
        int B, int M)
{
    const int b     = blockIdx.x;
    const int tid   = threadIdx.x;
    const int wave  = tid >> 6;
    const int lane  = tid & 63;
    const int h     = wave >> 1;
    const int mhalf = M >> 1;
    const int mst   = (wave & 1) * mhalf;

    __shared__ float A_lds[4][DIMV];
    __shared__ float S_lds[4];

    // ---- hyp_item: q = proj(expmap0(item_vec)); y2 = ||q||^2 ----
    // (reference applies proj twice; second proj is identity since ||q||<=maxnorm)
    const int it = items[b];                       // blockIdx-uniform -> scalar
    const float iv = ent[(long)it * DIMV + lane];
    float q, y2;
    {
        float n2 = wave_sum64(iv * iv);
        float n  = fmaxf(sqrtf(n2), F_MINN);
        float te = tanhf(n);
        float s  = (te > F_MAXN) ? (F_MAXN / te) : 1.0f;
        q  = iv * (te / n) * s;
        float qn = te * s;
        y2 = qn * qn;
    }

    // ---- per-(h,m) tasks: att + klein(t) accumulation ----
    float accA = 0.0f;   // sum_m p1 * kle_t[lane]
    float accS = 0.0f;   // sum_m p1
    const long ibase = ((long)h * B + b) * M + mst;

    for (int k = 0; k < mhalf; ++k) {
        const int ih  = __builtin_amdgcn_readfirstlane(mem_h[ibase + k]);
        const int ir  = __builtin_amdgcn_readfirstlane(mem_r[ibase + k]);
        const int itt = __builtin_amdgcn_readfirstlane(mem_t[ibase + k]);

        // u = (R/10) @ h_vec ; lane i computes row i, h via scalar (SGPR) loads
        const float*  hp = ent + (long)ih * DIMV;
        const float4* Rr = (const float4*)(rel + (long)ir * (DIMV * DIMV))
                           + lane * (DIMV / 4);
        float u = 0.0f;
#pragma unroll
        for (int kk = 0; kk < DIMV / 4; ++kk) {
            float4 rv = Rr[kk];
            u = fmaf(rv.x, hp[4 * kk + 0], u);
            u = fmaf(rv.y, hp[4 * kk + 1], u);
            u = fmaf(rv.z, hp[4 * kk + 2], u);
            u = fmaf(rv.w, hp[4 * kk + 3], u);
        }
        u *= 0.1f;

        // Rh = proj(expmap0(u));  ||Rh|| = min(tanh(||u||), maxnorm)
        float uu = wave_sum64(u * u);
        float nu = fmaxf(sqrtf(uu), F_MINN);
        float te = tanhf(nu);
        float sc = (te > F_MAXN) ? (F_MAXN / te) : 1.0f;
        float p  = u * (te / nu) * sc;
        float pn = te * sc;
        float x2 = pn * pn;

        // dist^2( Rh , q ) via scalar mobius formula (x = -Rh)
        float xy  = -wave_sum64(p * q);
        float A_  = 1.0f + 2.0f * xy + y2;
        float B_  = 1.0f - x2;
        float nm2 = fmaxf(A_ * A_ * x2 + B_ * B_ * y2 + 2.0f * A_ * B_ * xy, 0.0f);
        float den = fmaxf(1.0f + 2.0f * xy + x2 * y2, 1e-15f);
        float v   = fminf(sqrtf(nm2) / den, 1.0f - F_EPS);
        float dd  = log1pf(v) - log1pf(-v);          // = 2*artanh(v)
        float d2  = dd * dd;
        float att = expf(-0.2f * d2 - 0.05f);

        // t path: kle_t = to_klein(proj(expmap0(t)));  lorentz factor analytic
        float tv  = ent[(long)itt * DIMV + lane];
        float ttn = wave_sum64(tv * tv);
        float nt  = fmaxf(sqrtf(ttn), F_MINN);
        float tte = tanhf(nt);
        float ts  = (tte > F_MAXN) ? (F_MAXN / tte) : 1.0f;
        float pt  = tv * (tte / nt) * ts;
        float a2  = (tte * ts) * (tte * ts);         // ||proj t||^2
        float kle = 2.0f * pt / (1.0f + a2);
        float kn2 = 4.0f * a2 / ((1.0f + a2) * (1.0f + a2));  // ||kle_t||^2
        float lf  = 1.0f / sqrtf(fmaxf(1.0f - kn2, F_EPS));
        float p1  = lf * att;

        accS += p1;
        accA = fmaf(p1, kle, accA);
    }

    A_lds[wave][lane] = accA;
    if (lane == 0) S_lds[wave] = accS;
    __syncthreads();

    if (wave == 0) {
        // kle_o per h
        float k0 = (A_lds[0][lane] + A_lds[1][lane]) / fmaxf(S_lds[0] + S_lds[1], F_EPS);
        float k1 = (A_lds[2][lane] + A_lds[3][lane]) / fmaxf(S_lds[2] + S_lds[3], F_EPS);
        float n0 = wave_sum64(k0 * k0);
        float n1 = wave_sum64(k1 * k1);
        float p20 = 1.0f / sqrtf(fmaxf(1.0f - n0, F_EPS));
        float p21 = 1.0f / sqrtf(fmaxf(1.0f - n1, F_EPS));
        float ws  = fmaxf(p20 + p21, F_EPS);
        float o   = (p20 * k0 + p21 * k1) / ws;

        // hyp_o = proj(klein_to(o))
        float oo = wave_sum64(o * o);
        float kd = 1.0f + sqrtf(fmaxf(1.0f - oo, F_EPS));
        float ko = o / kd;
        float ko2 = oo / (kd * kd);
        float nk = fmaxf(sqrtf(ko2), F_MINN);
        float ps = (nk > F_MAXN) ? (F_MAXN / nk) : 1.0f;
        float hp = ko * ps;
        float x2 = (nk * ps) * (nk * ps);

        // d2 = sqdist(hyp_o, q)
        float xy  = -wave_sum64(hp * q);
        float A_  = 1.0f + 2.0f * xy + y2;
        float B_  = 1.0f - x2;
        float nm2 = fmaxf(A_ * A_ * x2 + B_ * B_ * y2 + 2.0f * A_ * B_ * xy, 0.0f);
        float den = fmaxf(1.0f + 2.0f * xy + x2 * y2, 1e-15f);
        float v   = fminf(sqrtf(nm2) / den, 1.0f - F_EPS);
        float dd  = log1pf(v) - log1pf(-v);
        float d2  = dd * dd;

        float scr = 1.0f / (expf(fminf(d2 - 2.0f, 40.0f)) + 1.0f);
        if (lane == 0) out[b] = scr;
    }
}

extern "C" void kernel_launch(void* const* d_in, const int* in_sizes, int n_in,
                              void* d_out, int out_size, void* d_ws, size_t ws_size,
                              hipStream_t stream) {
    // setup_inputs order:
    // 0 users(unused) 1 items 2 labels(unused) 3 mem_h 4 mem_r 5 mem_t
    // 6 entity_emb 7 rela_plus_emb(unused) 8 relation_emb
    const int*   items = (const int*)d_in[1];
    const int*   mh    = (const int*)d_in[3];
    const int*   mr    = (const int*)d_in[4];
    const int*   mt    = (const int*)d_in[5];
    const float* ent   = (const float*)d_in[6];
    const float* rel   = (const float*)d_in[8];
    float* out = (float*)d_out;

    const int B = in_sizes[1];              // 1024
    const int M = in_sizes[3] / (2 * B);    // 32  (H = 2)

    hpnet_kernel<<<dim3(B), dim3(256), 0, stream>>>(items, mh, mr, mt, ent, rel,
                                                    out, B, M);
}